// Round 1
// baseline (1242.089 us; speedup 1.0000x reference)
//
#include <hip/hip_runtime.h>
#include <hip/hip_bf16.h>

// Problem constants (match reference)
static constexpr int CH     = 128;   // IN_CH == HID
static constexpr int NCLS   = 32;
static constexpr int NGRAPH = 256;

// ---------------------------------------------------------------------------
// CSR build: count -> scan -> fill
// ---------------------------------------------------------------------------
__global__ void k_count(const int* __restrict__ dst, int* __restrict__ cnt, int E) {
  int i = blockIdx.x * 256 + threadIdx.x;
  if (i < E) atomicAdd(&cnt[dst[i]], 1);
}

__global__ void k_blocksum(const int* __restrict__ cnt, int* __restrict__ bsum, int N) {
  __shared__ int s[256];
  int i = blockIdx.x * 256 + threadIdx.x;
  s[threadIdx.x] = (i < N) ? cnt[i] : 0;
  __syncthreads();
  for (int st = 128; st > 0; st >>= 1) {
    if (threadIdx.x < st) s[threadIdx.x] += s[threadIdx.x + st];
    __syncthreads();
  }
  if (threadIdx.x == 0) bsum[blockIdx.x] = s[0];
}

// single block, 512 threads; NB <= 512
__global__ void k_scan_top(const int* __restrict__ bsum, int* __restrict__ boff,
                           int* __restrict__ offs_total, int NB) {
  __shared__ int s[512];
  int t = threadIdx.x;
  int v0 = (t < NB) ? bsum[t] : 0;
  s[t] = v0;
  __syncthreads();
  for (int st = 1; st < 512; st <<= 1) {
    int v = (t >= st) ? s[t - st] : 0;
    __syncthreads();
    s[t] += v;
    __syncthreads();
  }
  if (t < NB) boff[t] = s[t] - v0;          // exclusive block offset
  if (t == 0) offs_total[0] = s[511];        // total (= E)
}

__global__ void k_scan_final(const int* __restrict__ cnt, const int* __restrict__ boff,
                             int* __restrict__ offs, int* __restrict__ cursor, int N) {
  __shared__ int s[256];
  int i = blockIdx.x * 256 + threadIdx.x;
  int t = threadIdx.x;
  int c = (i < N) ? cnt[i] : 0;
  s[t] = c;
  __syncthreads();
  for (int st = 1; st < 256; st <<= 1) {
    int v = (t >= st) ? s[t - st] : 0;
    __syncthreads();
    s[t] += v;
    __syncthreads();
  }
  if (i < N) {
    int ex = boff[blockIdx.x] + s[t] - c;    // exclusive scan value
    offs[i]   = ex;
    cursor[i] = ex;
  }
}

__global__ void k_dinv(const int* __restrict__ cnt, float* __restrict__ dinv, int N) {
  int i = blockIdx.x * 256 + threadIdx.x;
  if (i < N) dinv[i] = 1.0f / sqrtf((float)(cnt[i] + 1));  // +1 self-loop
}

__global__ void k_fill(const int* __restrict__ src, const int* __restrict__ dst,
                       int* __restrict__ cursor, int* __restrict__ csr, int E) {
  int i = blockIdx.x * 256 + threadIdx.x;
  if (i < E) {
    int p = atomicAdd(&cursor[dst[i]], 1);
    csr[p] = src[i];
  }
}

// ---------------------------------------------------------------------------
// GEMM: C[r][:] = (A[r][:] @ W) * dinv[r]       A:[M,128]  W:[128,128]
// 128x128 block tile, BK=32, 256 threads, 8x8 microtile
// ---------------------------------------------------------------------------
__global__ __launch_bounds__(256) void k_gemm_scale(
    const float* __restrict__ A, const float* __restrict__ W,
    const float* __restrict__ dinv, float* __restrict__ C, int M) {
  __shared__ float As[128][33];   // +1 pad breaks bank conflicts on column reads
  __shared__ float Bs[32][128];
  int tid = threadIdx.x;
  int tx = tid & 15, ty = tid >> 4;       // 16 x 16 thread grid
  int row0 = blockIdx.x * 128;
  float acc[8][8];
  #pragma unroll
  for (int i = 0; i < 8; ++i)
    #pragma unroll
    for (int j = 0; j < 8; ++j) acc[i][j] = 0.0f;

  for (int k0 = 0; k0 < CH; k0 += 32) {
    // stage A tile: 128 rows x 32 cols (1024 float4, 4 per thread)
    #pragma unroll
    for (int l = 0; l < 4; ++l) {
      int i = tid + l * 256;
      int r = i >> 3, c4 = (i & 7) << 2;
      int rr = row0 + r; if (rr >= M) rr = M - 1;        // clamp (store is guarded)
      float4 v = *(const float4*)(A + (size_t)rr * CH + k0 + c4);
      As[r][c4 + 0] = v.x; As[r][c4 + 1] = v.y;
      As[r][c4 + 2] = v.z; As[r][c4 + 3] = v.w;
    }
    // stage W tile: 32 rows x 128 cols (1024 float4, 4 per thread)
    #pragma unroll
    for (int l = 0; l < 4; ++l) {
      int i = tid + l * 256;
      int r = i >> 5, c4 = (i & 31) << 2;
      *(float4*)&Bs[r][c4] = *(const float4*)(W + (size_t)(k0 + r) * CH + c4);
    }
    __syncthreads();
    #pragma unroll
    for (int kk = 0; kk < 32; ++kk) {
      float a[8];
      #pragma unroll
      for (int i = 0; i < 8; ++i) a[i] = As[ty * 8 + i][kk];
      float4 b0 = *(const float4*)&Bs[kk][tx * 8];
      float4 b1 = *(const float4*)&Bs[kk][tx * 8 + 4];
      float b[8] = {b0.x, b0.y, b0.z, b0.w, b1.x, b1.y, b1.z, b1.w};
      #pragma unroll
      for (int i = 0; i < 8; ++i)
        #pragma unroll
        for (int j = 0; j < 8; ++j) acc[i][j] = fmaf(a[i], b[j], acc[i][j]);
    }
    __syncthreads();
  }
  #pragma unroll
  for (int i = 0; i < 8; ++i) {
    int r = row0 + ty * 8 + i;
    if (r < M) {
      float d = dinv[r];
      float4 o0 = {acc[i][0] * d, acc[i][1] * d, acc[i][2] * d, acc[i][3] * d};
      float4 o1 = {acc[i][4] * d, acc[i][5] * d, acc[i][6] * d, acc[i][7] * d};
      *(float4*)(C + (size_t)r * CH + tx * 8)     = o0;
      *(float4*)(C + (size_t)r * CH + tx * 8 + 4) = o1;
    }
  }
}

// ---------------------------------------------------------------------------
// Aggregation (pull, CSR): out[n] = relu((sum_{e in N(n)} xs[src] + xs[n]) * dinv[n] + b)
// xs rows are pre-scaled by dinv[src]. One wave (64 lanes) per node, float2/lane.
// ---------------------------------------------------------------------------
__global__ __launch_bounds__(256) void k_agg(
    const float* __restrict__ xs, const int* __restrict__ csr,
    const int* __restrict__ offs, const float* __restrict__ dinv,
    const float* __restrict__ bias, float* __restrict__ out, int N) {
  int node = blockIdx.x * 4 + (threadIdx.x >> 6);
  int lane = threadIdx.x & 63;
  if (node >= N) return;
  int beg = offs[node], end = offs[node + 1];
  const float2* base = (const float2*)xs;
  float2 self = base[(size_t)node * 64 + lane];   // self-loop term (pre-scaled)
  float ax = self.x, ay = self.y;
  float bx2 = 0.f, by2 = 0.f;                     // second accumulator for ILP
  int e = beg;
  for (; e + 3 < end; e += 4) {
    int s0 = csr[e], s1 = csr[e + 1], s2 = csr[e + 2], s3 = csr[e + 3];
    float2 v0 = base[(size_t)s0 * 64 + lane];
    float2 v1 = base[(size_t)s1 * 64 + lane];
    float2 v2 = base[(size_t)s2 * 64 + lane];
    float2 v3 = base[(size_t)s3 * 64 + lane];
    ax += v0.x + v2.x; ay += v0.y + v2.y;
    bx2 += v1.x + v3.x; by2 += v1.y + v3.y;
  }
  for (; e < end; ++e) {
    int s = csr[e];
    float2 v = base[(size_t)s * 64 + lane];
    ax += v.x; ay += v.y;
  }
  ax += bx2; ay += by2;
  float d = dinv[node];
  float rx = fmaf(ax, d, bias[2 * lane]);
  float ry = fmaf(ay, d, bias[2 * lane + 1]);
  float2 r = {fmaxf(rx, 0.f), fmaxf(ry, 0.f)};
  ((float2*)out)[(size_t)node * 64 + lane] = r;
}

// ---------------------------------------------------------------------------
// Pool: batch is sorted -> run-length accumulate per block, few atomics
// ---------------------------------------------------------------------------
__global__ __launch_bounds__(128) void k_pool(
    const float* __restrict__ h, const int* __restrict__ batch,
    float* __restrict__ gsum, int N) {
  int ch = threadIdx.x;                 // 0..127
  int n0 = blockIdx.x * 128;
  int n1 = n0 + 128; if (n1 > N) n1 = N;
  if (n0 >= N) return;
  float acc = 0.f;
  int curg = batch[n0];
  for (int n = n0; n < n1; ++n) {
    int g = batch[n];                   // uniform per iteration -> broadcast
    if (g != curg) {
      atomicAdd(&gsum[curg * CH + ch], acc);
      acc = 0.f; curg = g;
    }
    acc += h[(size_t)n * CH + ch];
  }
  atomicAdd(&gsum[curg * CH + ch], acc);
}

__global__ void k_gcnt(const int* __restrict__ batch, int* __restrict__ gcnt, int N) {
  int i = blockIdx.x * 256 + threadIdx.x;
  if (i < N) atomicAdd(&gcnt[batch[i]], 1);
}

// ---------------------------------------------------------------------------
// FC: out[g][j] = bfc[j] + (1/max(cnt,1)) * sum_c gsum[g][c] * Wfc[c][j]
// ---------------------------------------------------------------------------
__global__ __launch_bounds__(64) void k_fc(
    const float* __restrict__ gsum, const int* __restrict__ gcnt,
    const float* __restrict__ Wfc, const float* __restrict__ bfc,
    float* __restrict__ outp) {
  int g = blockIdx.x;
  int j = threadIdx.x;
  if (j >= NCLS) return;
  float invc = 1.0f / fmaxf((float)gcnt[g], 1.0f);
  float acc = 0.0f;
  for (int c = 0; c < CH; ++c)
    acc = fmaf(gsum[g * CH + c], Wfc[c * NCLS + j], acc);
  outp[g * NCLS + j] = fmaf(acc, invc, bfc[j]);
}

// ---------------------------------------------------------------------------
extern "C" void kernel_launch(void* const* d_in, const int* in_sizes, int n_in,
                              void* d_out, int out_size, void* d_ws, size_t ws_size,
                              hipStream_t stream) {
  const float* x    = (const float*)d_in[0];
  const int*   ei   = (const int*)d_in[1];
  const int*   batch= (const int*)d_in[2];
  const float* W1   = (const float*)d_in[3];
  const float* b1   = (const float*)d_in[4];
  const float* W2   = (const float*)d_in[5];
  const float* b2   = (const float*)d_in[6];
  const float* Wfc  = (const float*)d_in[7];
  const float* bfc  = (const float*)d_in[8];
  float* outp = (float*)d_out;

  const int N = in_sizes[0] / CH;       // 100000
  const int E = in_sizes[1] / 2;        // 3200000
  const int* src = ei;
  const int* dst = ei + E;

  // Workspace carve (256B aligned)
  char* w = (char*)d_ws;
  size_t o = 0;
  auto carve = [&](size_t bytes) -> void* {
    o = (o + 255) & ~(size_t)255;
    void* p = w + o;
    o += bytes;
    return p;
  };
  int*   cnt    = (int*)  carve((size_t)N * 4);
  int*   offs   = (int*)  carve((size_t)(N + 1) * 4);
  int*   cursor = (int*)  carve((size_t)N * 4);
  int*   bsum   = (int*)  carve(512 * 4);
  int*   boff   = (int*)  carve(512 * 4);
  int*   csr    = (int*)  carve((size_t)E * 4);
  float* dinv   = (float*)carve((size_t)N * 4);
  float* bufA   = (float*)carve((size_t)N * CH * 4);   // xs / hs (pre-scaled)
  float* bufB   = (float*)carve((size_t)N * CH * 4);   // h / h2
  float* gsum   = (float*)carve((size_t)NGRAPH * CH * 4);
  int*   gcnt   = (int*)  carve((size_t)NGRAPH * 4);
  (void)ws_size;

  // Zero the accumulated buffers (ws is poisoned 0xAA before every launch)
  hipMemsetAsync(cnt,  0, (size_t)N * 4, stream);
  hipMemsetAsync(gsum, 0, (size_t)NGRAPH * CH * 4, stream);
  hipMemsetAsync(gcnt, 0, (size_t)NGRAPH * 4, stream);

  const int NB  = (N + 255) / 256;      // 391
  const int EB  = (E + 255) / 256;      // 12500

  // CSR + degrees
  k_count<<<EB, 256, 0, stream>>>(dst, cnt, E);
  k_blocksum<<<NB, 256, 0, stream>>>(cnt, bsum, N);
  k_scan_top<<<1, 512, 0, stream>>>(bsum, boff, offs + N, NB);
  k_scan_final<<<NB, 256, 0, stream>>>(cnt, boff, offs, cursor, N);
  k_dinv<<<NB, 256, 0, stream>>>(cnt, dinv, N);
  k_fill<<<EB, 256, 0, stream>>>(src, dst, cursor, csr, E);

  const int GB = (N + 127) / 128;       // 782 blocks for GEMM / pool
  const int AB = (N + 3) / 4;           // 25000 blocks for agg

  // Layer 1
  k_gemm_scale<<<GB, 256, 0, stream>>>(x, W1, dinv, bufA, N);
  k_agg<<<AB, 256, 0, stream>>>(bufA, csr, offs, dinv, b1, bufB, N);
  // Layer 2
  k_gemm_scale<<<GB, 256, 0, stream>>>(bufB, W2, dinv, bufA, N);
  k_agg<<<AB, 256, 0, stream>>>(bufA, csr, offs, dinv, b2, bufB, N);

  // Pool + FC
  k_pool<<<GB, 128, 0, stream>>>(bufB, batch, gsum, N);
  k_gcnt<<<NB, 256, 0, stream>>>(batch, gcnt, N);
  k_fc<<<NGRAPH, 64, 0, stream>>>(gsum, gcnt, Wfc, bfc, outp);
  (void)out_size; (void)n_in;
}

// Round 2
// 925.247 us; speedup vs baseline: 1.3424x; 1.3424x over previous
//
#include <hip/hip_runtime.h>
#include <hip/hip_bf16.h>

// Problem constants (match reference)
static constexpr int CH     = 128;   // IN_CH == HID
static constexpr int NCLS   = 32;
static constexpr int NGRAPH = 256;

// Bucketed CSR build: buckets are 512-node ranges (bucket = dst >> 9).
// N=100000 -> NBUCK=196 (< 256; arrays sized 256).
static constexpr int BSHIFT = 9;
static constexpr int BW     = 1 << BSHIFT;   // 512 nodes per bucket
static constexpr int MAXB   = 256;

// ---------------------------------------------------------------------------
// 1) bucket histogram (LDS-aggregated)
// ---------------------------------------------------------------------------
__global__ __launch_bounds__(256) void k_hist(const int* __restrict__ dst,
                                              int* __restrict__ gbcnt, int E) {
  __shared__ int h[MAXB];
  int t = threadIdx.x;
  h[t] = 0;
  __syncthreads();
  for (int i = blockIdx.x * 256 + t; i < E; i += gridDim.x * 256)
    atomicAdd(&h[dst[i] >> BSHIFT], 1);
  __syncthreads();
  if (h[t]) atomicAdd(&gbcnt[t], h[t]);
}

// ---------------------------------------------------------------------------
// 2) scan bucket counts -> ebase[257]; init bucket cursors
// ---------------------------------------------------------------------------
__global__ __launch_bounds__(256) void k_bscan(const int* __restrict__ gbcnt,
                                               int* __restrict__ ebase,
                                               int* __restrict__ gcur) {
  __shared__ int s[MAXB];
  int t = threadIdx.x;
  int v0 = gbcnt[t];
  s[t] = v0;
  __syncthreads();
  for (int st = 1; st < MAXB; st <<= 1) {
    int v = (t >= st) ? s[t - st] : 0;
    __syncthreads();
    s[t] += v;
    __syncthreads();
  }
  int ex = s[t] - v0;
  ebase[t] = ex;
  gcur[t]  = ex;
  if (t == MAXB - 1) ebase[MAXB] = s[t];
}

// ---------------------------------------------------------------------------
// 3) scatter (src,dst) pairs into bucket-ordered edge array.
//    8192 edges/block, LDS rank -> one global atomic per (block,bucket),
//    writes land in ~256B runs per bucket.
// ---------------------------------------------------------------------------
__global__ __launch_bounds__(1024) void k_scatter(
    const int* __restrict__ src, const int* __restrict__ dst,
    int* __restrict__ gcur, int2* __restrict__ ebuf, int E) {
  __shared__ int bcnt[MAXB];
  __shared__ int bbase[MAXB];
  int t = threadIdx.x;
  if (t < MAXB) bcnt[t] = 0;
  __syncthreads();
  int base = blockIdx.x * 8192;
  int s_[8], d_[8], r_[8];
  #pragma unroll
  for (int j = 0; j < 8; ++j) {
    int i = base + j * 1024 + t;
    if (i < E) {
      s_[j] = src[i];
      d_[j] = dst[i];
      r_[j] = atomicAdd(&bcnt[d_[j] >> BSHIFT], 1);
    }
  }
  __syncthreads();
  if (t < MAXB && bcnt[t]) bbase[t] = atomicAdd(&gcur[t], bcnt[t]);
  __syncthreads();
  #pragma unroll
  for (int j = 0; j < 8; ++j) {
    int i = base + j * 1024 + t;
    if (i < E) {
      int b = d_[j] >> BSHIFT;
      ebuf[bbase[b] + r_[j]] = make_int2(s_[j], d_[j]);
    }
  }
}

// ---------------------------------------------------------------------------
// 4) per-bucket CSR build: degree count + scan in LDS, write offs/dinv
//    coalesced, fill csr via LDS cursors (writes stay in a ~65KB L2 window).
// ---------------------------------------------------------------------------
__global__ __launch_bounds__(1024) void k_build(
    const int2* __restrict__ ebuf, const int* __restrict__ ebase,
    int* __restrict__ offs, float* __restrict__ dinv,
    int* __restrict__ csr, int N, int E, int NBUCK) {
  __shared__ int sdeg[BW];
  __shared__ int sscan[BW];
  int b = blockIdx.x;
  int t = threadIdx.x;
  int lo = b << BSHIFT;
  int e0 = ebase[b], e1 = ebase[b + 1];

  if (t < BW) sdeg[t] = 0;
  __syncthreads();
  for (int e = e0 + t; e < e1; e += 1024)
    atomicAdd(&sdeg[ebuf[e].y - lo], 1);
  __syncthreads();
  // inclusive scan of sdeg -> sscan
  if (t < BW) sscan[t] = sdeg[t];
  __syncthreads();
  for (int st = 1; st < BW; st <<= 1) {
    int v = (t < BW && t >= st) ? sscan[t - st] : 0;
    __syncthreads();
    if (t < BW) sscan[t] += v;
    __syncthreads();
  }
  if (t < BW) {
    int ex = e0 + sscan[t] - sdeg[t];   // global csr offset of node lo+t
    int n = lo + t;
    if (n < N) {
      offs[n] = ex;
      dinv[n] = 1.0f / sqrtf((float)(sdeg[t] + 1));
    }
    sscan[t] = ex;                       // becomes the fill cursor
  }
  if (b == NBUCK - 1 && t == 0) offs[N] = E;
  __syncthreads();
  for (int e = e0 + t; e < e1; e += 1024) {
    int2 p = ebuf[e];
    int pos = atomicAdd(&sscan[p.y - lo], 1);
    csr[pos] = p.x;
  }
}

// ---------------------------------------------------------------------------
// GEMM: C[r][:] = (A[r][:] @ W) * dinv[r]       A:[M,128]  W:[128,128]
// 128x128 block tile, BK=32, 256 threads, 8x8 microtile
// ---------------------------------------------------------------------------
__global__ __launch_bounds__(256) void k_gemm_scale(
    const float* __restrict__ A, const float* __restrict__ W,
    const float* __restrict__ dinv, float* __restrict__ C, int M) {
  __shared__ float As[128][33];
  __shared__ float Bs[32][128];
  int tid = threadIdx.x;
  int tx = tid & 15, ty = tid >> 4;
  int row0 = blockIdx.x * 128;
  float acc[8][8];
  #pragma unroll
  for (int i = 0; i < 8; ++i)
    #pragma unroll
    for (int j = 0; j < 8; ++j) acc[i][j] = 0.0f;

  for (int k0 = 0; k0 < CH; k0 += 32) {
    #pragma unroll
    for (int l = 0; l < 4; ++l) {
      int i = tid + l * 256;
      int r = i >> 3, c4 = (i & 7) << 2;
      int rr = row0 + r; if (rr >= M) rr = M - 1;
      float4 v = *(const float4*)(A + (size_t)rr * CH + k0 + c4);
      As[r][c4 + 0] = v.x; As[r][c4 + 1] = v.y;
      As[r][c4 + 2] = v.z; As[r][c4 + 3] = v.w;
    }
    #pragma unroll
    for (int l = 0; l < 4; ++l) {
      int i = tid + l * 256;
      int r = i >> 5, c4 = (i & 31) << 2;
      *(float4*)&Bs[r][c4] = *(const float4*)(W + (size_t)(k0 + r) * CH + c4);
    }
    __syncthreads();
    #pragma unroll
    for (int kk = 0; kk < 32; ++kk) {
      float a[8];
      #pragma unroll
      for (int i = 0; i < 8; ++i) a[i] = As[ty * 8 + i][kk];
      float4 b0 = *(const float4*)&Bs[kk][tx * 8];
      float4 b1 = *(const float4*)&Bs[kk][tx * 8 + 4];
      float b[8] = {b0.x, b0.y, b0.z, b0.w, b1.x, b1.y, b1.z, b1.w};
      #pragma unroll
      for (int i = 0; i < 8; ++i)
        #pragma unroll
        for (int j = 0; j < 8; ++j) acc[i][j] = fmaf(a[i], b[j], acc[i][j]);
    }
    __syncthreads();
  }
  #pragma unroll
  for (int i = 0; i < 8; ++i) {
    int r = row0 + ty * 8 + i;
    if (r < M) {
      float d = dinv[r];
      float4 o0 = {acc[i][0] * d, acc[i][1] * d, acc[i][2] * d, acc[i][3] * d};
      float4 o1 = {acc[i][4] * d, acc[i][5] * d, acc[i][6] * d, acc[i][7] * d};
      *(float4*)(C + (size_t)r * CH + tx * 8)     = o0;
      *(float4*)(C + (size_t)r * CH + tx * 8 + 4) = o1;
    }
  }
}

// ---------------------------------------------------------------------------
// Aggregation (pull, CSR): out[n] = relu((sum_{N(n)} xs[src] + xs[n])*dinv[n] + b)
// ---------------------------------------------------------------------------
__global__ __launch_bounds__(256) void k_agg(
    const float* __restrict__ xs, const int* __restrict__ csr,
    const int* __restrict__ offs, const float* __restrict__ dinv,
    const float* __restrict__ bias, float* __restrict__ out, int N) {
  int node = blockIdx.x * 4 + (threadIdx.x >> 6);
  int lane = threadIdx.x & 63;
  if (node >= N) return;
  int beg = offs[node], end = offs[node + 1];
  const float2* base = (const float2*)xs;
  float2 self = base[(size_t)node * 64 + lane];
  float ax = self.x, ay = self.y;
  float bx2 = 0.f, by2 = 0.f;
  int e = beg;
  for (; e + 3 < end; e += 4) {
    int s0 = csr[e], s1 = csr[e + 1], s2 = csr[e + 2], s3 = csr[e + 3];
    float2 v0 = base[(size_t)s0 * 64 + lane];
    float2 v1 = base[(size_t)s1 * 64 + lane];
    float2 v2 = base[(size_t)s2 * 64 + lane];
    float2 v3 = base[(size_t)s3 * 64 + lane];
    ax += v0.x + v2.x; ay += v0.y + v2.y;
    bx2 += v1.x + v3.x; by2 += v1.y + v3.y;
  }
  for (; e < end; ++e) {
    int s = csr[e];
    float2 v = base[(size_t)s * 64 + lane];
    ax += v.x; ay += v.y;
  }
  ax += bx2; ay += by2;
  float d = dinv[node];
  float rx = fmaf(ax, d, bias[2 * lane]);
  float ry = fmaf(ay, d, bias[2 * lane + 1]);
  float2 r = {fmaxf(rx, 0.f), fmaxf(ry, 0.f)};
  ((float2*)out)[(size_t)node * 64 + lane] = r;
}

// ---------------------------------------------------------------------------
// Pool: batch sorted -> run-length accumulate, few atomics
// ---------------------------------------------------------------------------
__global__ __launch_bounds__(128) void k_pool(
    const float* __restrict__ h, const int* __restrict__ batch,
    float* __restrict__ gsum, int N) {
  int ch = threadIdx.x;
  int n0 = blockIdx.x * 128;
  int n1 = n0 + 128; if (n1 > N) n1 = N;
  if (n0 >= N) return;
  float acc = 0.f;
  int curg = batch[n0];
  for (int n = n0; n < n1; ++n) {
    int g = batch[n];
    if (g != curg) {
      atomicAdd(&gsum[curg * CH + ch], acc);
      acc = 0.f; curg = g;
    }
    acc += h[(size_t)n * CH + ch];
  }
  atomicAdd(&gsum[curg * CH + ch], acc);
}

__global__ void k_gcnt(const int* __restrict__ batch, int* __restrict__ gcnt, int N) {
  int i = blockIdx.x * 256 + threadIdx.x;
  if (i < N) atomicAdd(&gcnt[batch[i]], 1);
}

// ---------------------------------------------------------------------------
// FC
// ---------------------------------------------------------------------------
__global__ __launch_bounds__(64) void k_fc(
    const float* __restrict__ gsum, const int* __restrict__ gcnt,
    const float* __restrict__ Wfc, const float* __restrict__ bfc,
    float* __restrict__ outp) {
  int g = blockIdx.x;
  int j = threadIdx.x;
  if (j >= NCLS) return;
  float invc = 1.0f / fmaxf((float)gcnt[g], 1.0f);
  float acc = 0.0f;
  for (int c = 0; c < CH; ++c)
    acc = fmaf(gsum[g * CH + c], Wfc[c * NCLS + j], acc);
  outp[g * NCLS + j] = fmaf(acc, invc, bfc[j]);
}

// ---------------------------------------------------------------------------
extern "C" void kernel_launch(void* const* d_in, const int* in_sizes, int n_in,
                              void* d_out, int out_size, void* d_ws, size_t ws_size,
                              hipStream_t stream) {
  const float* x    = (const float*)d_in[0];
  const int*   ei   = (const int*)d_in[1];
  const int*   batch= (const int*)d_in[2];
  const float* W1   = (const float*)d_in[3];
  const float* b1   = (const float*)d_in[4];
  const float* W2   = (const float*)d_in[5];
  const float* b2   = (const float*)d_in[6];
  const float* Wfc  = (const float*)d_in[7];
  const float* bfc  = (const float*)d_in[8];
  float* outp = (float*)d_out;

  const int N = in_sizes[0] / CH;       // 100000
  const int E = in_sizes[1] / 2;        // 3200000
  const int* src = ei;
  const int* dst = ei + E;
  const int NBUCK = (N + BW - 1) >> BSHIFT;   // 196

  // Workspace carve (256B aligned)
  char* w = (char*)d_ws;
  size_t o = 0;
  auto carve = [&](size_t bytes) -> void* {
    o = (o + 255) & ~(size_t)255;
    void* p = w + o;
    o += bytes;
    return p;
  };
  int*   offs   = (int*)  carve((size_t)(N + 1) * 4);
  int*   gbcnt  = (int*)  carve(MAXB * 4);
  int*   ebase  = (int*)  carve((MAXB + 1) * 4);
  int*   gcur   = (int*)  carve(MAXB * 4);
  int*   csr    = (int*)  carve((size_t)E * 4);
  float* dinv   = (float*)carve((size_t)N * 4);
  float* bufA   = (float*)carve((size_t)N * CH * 4);
  float* bufB   = (float*)carve((size_t)N * CH * 4);
  float* gsum   = (float*)carve((size_t)NGRAPH * CH * 4);
  int*   gcnt   = (int*)  carve((size_t)NGRAPH * 4);
  (void)ws_size;

  // ebuf (bucket-ordered edge pairs) aliases bufB: dead once k_build is done,
  // bufB is first written by agg layer-1 afterwards.
  int2* ebuf = (int2*)bufB;   // needs E*8 = 25.6MB <= 51.2MB

  hipMemsetAsync(gbcnt, 0, MAXB * 4, stream);
  hipMemsetAsync(gsum,  0, (size_t)NGRAPH * CH * 4, stream);
  hipMemsetAsync(gcnt,  0, (size_t)NGRAPH * 4, stream);

  // CSR build (bucketed counting sort)
  k_hist   <<<512, 256, 0, stream>>>(dst, gbcnt, E);
  k_bscan  <<<1, MAXB, 0, stream>>>(gbcnt, ebase, gcur);
  k_scatter<<<(E + 8191) / 8192, 1024, 0, stream>>>(src, dst, gcur, ebuf, E);
  k_build  <<<NBUCK, 1024, 0, stream>>>(ebuf, ebase, offs, dinv, csr, N, E, NBUCK);

  const int GB = (N + 127) / 128;
  const int AB = (N + 3) / 4;
  const int NB = (N + 255) / 256;

  // Layer 1
  k_gemm_scale<<<GB, 256, 0, stream>>>(x, W1, dinv, bufA, N);
  k_agg<<<AB, 256, 0, stream>>>(bufA, csr, offs, dinv, b1, bufB, N);
  // Layer 2
  k_gemm_scale<<<GB, 256, 0, stream>>>(bufB, W2, dinv, bufA, N);
  k_agg<<<AB, 256, 0, stream>>>(bufA, csr, offs, dinv, b2, bufB, N);

  // Pool + FC
  k_pool<<<GB, 128, 0, stream>>>(bufB, batch, gsum, N);
  k_gcnt<<<NB, 256, 0, stream>>>(batch, gcnt, N);
  k_fc<<<NGRAPH, 64, 0, stream>>>(gsum, gcnt, Wfc, bfc, outp);
  (void)out_size; (void)n_in;
}

// Round 3
// 721.846 us; speedup vs baseline: 1.7207x; 1.2818x over previous
//
#include <hip/hip_runtime.h>
#include <hip/hip_bf16.h>
#include <hip/hip_fp16.h>

// Problem constants (match reference)
static constexpr int CH     = 128;   // IN_CH == HID
static constexpr int NCLS   = 32;
static constexpr int NGRAPH = 256;

// Bucketed CSR build: buckets are 512-node ranges (bucket = dst >> 9).
static constexpr int BSHIFT = 9;
static constexpr int BW     = 1 << BSHIFT;   // 512 nodes per bucket
static constexpr int MAXB   = 256;

// ---------------------------------------------------------------------------
// 1) bucket histogram (LDS-aggregated)
// ---------------------------------------------------------------------------
__global__ __launch_bounds__(256) void k_hist(const int* __restrict__ dst,
                                              int* __restrict__ gbcnt, int E) {
  __shared__ int h[MAXB];
  int t = threadIdx.x;
  h[t] = 0;
  __syncthreads();
  for (int i = blockIdx.x * 256 + t; i < E; i += gridDim.x * 256)
    atomicAdd(&h[dst[i] >> BSHIFT], 1);
  __syncthreads();
  if (h[t]) atomicAdd(&gbcnt[t], h[t]);
}

// ---------------------------------------------------------------------------
// 2) scan bucket counts -> ebase[257]; init bucket cursors
// ---------------------------------------------------------------------------
__global__ __launch_bounds__(256) void k_bscan(const int* __restrict__ gbcnt,
                                               int* __restrict__ ebase,
                                               int* __restrict__ gcur) {
  __shared__ int s[MAXB];
  int t = threadIdx.x;
  int v0 = gbcnt[t];
  s[t] = v0;
  __syncthreads();
  for (int st = 1; st < MAXB; st <<= 1) {
    int v = (t >= st) ? s[t - st] : 0;
    __syncthreads();
    s[t] += v;
    __syncthreads();
  }
  int ex = s[t] - v0;
  ebase[t] = ex;
  gcur[t]  = ex;
  if (t == MAXB - 1) ebase[MAXB] = s[t];
}

// ---------------------------------------------------------------------------
// 3) scatter (src,dst) pairs into bucket-ordered edge array
// ---------------------------------------------------------------------------
__global__ __launch_bounds__(1024) void k_scatter(
    const int* __restrict__ src, const int* __restrict__ dst,
    int* __restrict__ gcur, int2* __restrict__ ebuf, int E) {
  __shared__ int bcnt[MAXB];
  __shared__ int bbase[MAXB];
  int t = threadIdx.x;
  if (t < MAXB) bcnt[t] = 0;
  __syncthreads();
  int base = blockIdx.x * 8192;
  int s_[8], d_[8], r_[8];
  #pragma unroll
  for (int j = 0; j < 8; ++j) {
    int i = base + j * 1024 + t;
    if (i < E) {
      s_[j] = src[i];
      d_[j] = dst[i];
      r_[j] = atomicAdd(&bcnt[d_[j] >> BSHIFT], 1);
    }
  }
  __syncthreads();
  if (t < MAXB && bcnt[t]) bbase[t] = atomicAdd(&gcur[t], bcnt[t]);
  __syncthreads();
  #pragma unroll
  for (int j = 0; j < 8; ++j) {
    int i = base + j * 1024 + t;
    if (i < E) {
      int b = d_[j] >> BSHIFT;
      ebuf[bbase[b] + r_[j]] = make_int2(s_[j], d_[j]);
    }
  }
}

// ---------------------------------------------------------------------------
// 4) per-bucket CSR build
// ---------------------------------------------------------------------------
__global__ __launch_bounds__(1024) void k_build(
    const int2* __restrict__ ebuf, const int* __restrict__ ebase,
    int* __restrict__ offs, float* __restrict__ dinv,
    int* __restrict__ csr, int N, int E, int NBUCK) {
  __shared__ int sdeg[BW];
  __shared__ int sscan[BW];
  int b = blockIdx.x;
  int t = threadIdx.x;
  int lo = b << BSHIFT;
  int e0 = ebase[b], e1 = ebase[b + 1];

  if (t < BW) sdeg[t] = 0;
  __syncthreads();
  for (int e = e0 + t; e < e1; e += 1024)
    atomicAdd(&sdeg[ebuf[e].y - lo], 1);
  __syncthreads();
  if (t < BW) sscan[t] = sdeg[t];
  __syncthreads();
  for (int st = 1; st < BW; st <<= 1) {
    int v = (t < BW && t >= st) ? sscan[t - st] : 0;
    __syncthreads();
    if (t < BW) sscan[t] += v;
    __syncthreads();
  }
  if (t < BW) {
    int ex = e0 + sscan[t] - sdeg[t];
    int n = lo + t;
    if (n < N) {
      offs[n] = ex;
      dinv[n] = 1.0f / sqrtf((float)(sdeg[t] + 1));
    }
    sscan[t] = ex;
  }
  if (b == NBUCK - 1 && t == 0) offs[N] = E;
  __syncthreads();
  for (int e = e0 + t; e < e1; e += 1024) {
    int2 p = ebuf[e];
    int pos = atomicAdd(&sscan[p.y - lo], 1);
    csr[pos] = p.x;
  }
}

// ---------------------------------------------------------------------------
// GEMM: C[r][:] = half( (A[r][:] @ W) * dinv[r] )     A:[M,128] fp32, C fp16
// 128x128 block tile, BK=32, 256 threads, 8x8 microtile
// ---------------------------------------------------------------------------
__global__ __launch_bounds__(256) void k_gemm_scale(
    const float* __restrict__ A, const float* __restrict__ W,
    const float* __restrict__ dinv, __half* __restrict__ C, int M) {
  __shared__ float As[128][33];
  __shared__ float Bs[32][128];
  int tid = threadIdx.x;
  int tx = tid & 15, ty = tid >> 4;
  int row0 = blockIdx.x * 128;
  float acc[8][8];
  #pragma unroll
  for (int i = 0; i < 8; ++i)
    #pragma unroll
    for (int j = 0; j < 8; ++j) acc[i][j] = 0.0f;

  for (int k0 = 0; k0 < CH; k0 += 32) {
    #pragma unroll
    for (int l = 0; l < 4; ++l) {
      int i = tid + l * 256;
      int r = i >> 3, c4 = (i & 7) << 2;
      int rr = row0 + r; if (rr >= M) rr = M - 1;
      float4 v = *(const float4*)(A + (size_t)rr * CH + k0 + c4);
      As[r][c4 + 0] = v.x; As[r][c4 + 1] = v.y;
      As[r][c4 + 2] = v.z; As[r][c4 + 3] = v.w;
    }
    #pragma unroll
    for (int l = 0; l < 4; ++l) {
      int i = tid + l * 256;
      int r = i >> 5, c4 = (i & 31) << 2;
      *(float4*)&Bs[r][c4] = *(const float4*)(W + (size_t)(k0 + r) * CH + c4);
    }
    __syncthreads();
    #pragma unroll
    for (int kk = 0; kk < 32; ++kk) {
      float a[8];
      #pragma unroll
      for (int i = 0; i < 8; ++i) a[i] = As[ty * 8 + i][kk];
      float4 b0 = *(const float4*)&Bs[kk][tx * 8];
      float4 b1 = *(const float4*)&Bs[kk][tx * 8 + 4];
      float b[8] = {b0.x, b0.y, b0.z, b0.w, b1.x, b1.y, b1.z, b1.w};
      #pragma unroll
      for (int i = 0; i < 8; ++i)
        #pragma unroll
        for (int j = 0; j < 8; ++j) acc[i][j] = fmaf(a[i], b[j], acc[i][j]);
    }
    __syncthreads();
  }
  #pragma unroll
  for (int i = 0; i < 8; ++i) {
    int r = row0 + ty * 8 + i;
    if (r < M) {
      float d = dinv[r];
      __half2 p0 = __floats2half2_rn(acc[i][0] * d, acc[i][1] * d);
      __half2 p1 = __floats2half2_rn(acc[i][2] * d, acc[i][3] * d);
      __half2 p2 = __floats2half2_rn(acc[i][4] * d, acc[i][5] * d);
      __half2 p3 = __floats2half2_rn(acc[i][6] * d, acc[i][7] * d);
      float4 ov;
      ((__half2*)&ov)[0] = p0; ((__half2*)&ov)[1] = p1;
      ((__half2*)&ov)[2] = p2; ((__half2*)&ov)[3] = p3;
      *((float4*)(C + (size_t)r * CH) + tx) = ov;   // 16B = 8 halfs
    }
  }
}

// ---------------------------------------------------------------------------
// Aggregation (pull, CSR): out[n] = relu((sum_{N(n)} xs[src] + xs[n])*dinv[n]+b)
// xs rows pre-scaled fp16 (256B/row, 4B/lane). Accumulate fp32, out fp32.
// ---------------------------------------------------------------------------
__global__ __launch_bounds__(256) void k_agg(
    const __half* __restrict__ xs, const int* __restrict__ csr,
    const int* __restrict__ offs, const float* __restrict__ dinv,
    const float* __restrict__ bias, float* __restrict__ out, int N) {
  int node = blockIdx.x * 4 + (threadIdx.x >> 6);
  int lane = threadIdx.x & 63;
  if (node >= N) return;
  int beg = offs[node], end = offs[node + 1];
  const __half2* base = (const __half2*)xs;
  float2 self = __half22float2(base[(size_t)node * 64 + lane]);
  float ax = self.x, ay = self.y;
  float bx2 = 0.f, by2 = 0.f;
  int e = beg;
  for (; e + 3 < end; e += 4) {
    int s0 = csr[e], s1 = csr[e + 1], s2 = csr[e + 2], s3 = csr[e + 3];
    float2 v0 = __half22float2(base[(size_t)s0 * 64 + lane]);
    float2 v1 = __half22float2(base[(size_t)s1 * 64 + lane]);
    float2 v2 = __half22float2(base[(size_t)s2 * 64 + lane]);
    float2 v3 = __half22float2(base[(size_t)s3 * 64 + lane]);
    ax += v0.x + v2.x; ay += v0.y + v2.y;
    bx2 += v1.x + v3.x; by2 += v1.y + v3.y;
  }
  for (; e < end; ++e) {
    int s = csr[e];
    float2 v = __half22float2(base[(size_t)s * 64 + lane]);
    ax += v.x; ay += v.y;
  }
  ax += bx2; ay += by2;
  float d = dinv[node];
  float rx = fmaf(ax, d, bias[2 * lane]);
  float ry = fmaf(ay, d, bias[2 * lane + 1]);
  float2 r = {fmaxf(rx, 0.f), fmaxf(ry, 0.f)};
  ((float2*)out)[(size_t)node * 64 + lane] = r;
}

// ---------------------------------------------------------------------------
// Pool: batch sorted -> run-length accumulate, few atomics
// ---------------------------------------------------------------------------
__global__ __launch_bounds__(128) void k_pool(
    const float* __restrict__ h, const int* __restrict__ batch,
    float* __restrict__ gsum, int N) {
  int ch = threadIdx.x;
  int n0 = blockIdx.x * 128;
  int n1 = n0 + 128; if (n1 > N) n1 = N;
  if (n0 >= N) return;
  float acc = 0.f;
  int curg = batch[n0];
  for (int n = n0; n < n1; ++n) {
    int g = batch[n];
    if (g != curg) {
      atomicAdd(&gsum[curg * CH + ch], acc);
      acc = 0.f; curg = g;
    }
    acc += h[(size_t)n * CH + ch];
  }
  atomicAdd(&gsum[curg * CH + ch], acc);
}

__global__ void k_gcnt(const int* __restrict__ batch, int* __restrict__ gcnt, int N) {
  int i = blockIdx.x * 256 + threadIdx.x;
  if (i < N) atomicAdd(&gcnt[batch[i]], 1);
}

// ---------------------------------------------------------------------------
// FC
// ---------------------------------------------------------------------------
__global__ __launch_bounds__(64) void k_fc(
    const float* __restrict__ gsum, const int* __restrict__ gcnt,
    const float* __restrict__ Wfc, const float* __restrict__ bfc,
    float* __restrict__ outp) {
  int g = blockIdx.x;
  int j = threadIdx.x;
  if (j >= NCLS) return;
  float invc = 1.0f / fmaxf((float)gcnt[g], 1.0f);
  float acc = 0.0f;
  for (int c = 0; c < CH; ++c)
    acc = fmaf(gsum[g * CH + c], Wfc[c * NCLS + j], acc);
  outp[g * NCLS + j] = fmaf(acc, invc, bfc[j]);
}

// ---------------------------------------------------------------------------
extern "C" void kernel_launch(void* const* d_in, const int* in_sizes, int n_in,
                              void* d_out, int out_size, void* d_ws, size_t ws_size,
                              hipStream_t stream) {
  const float* x    = (const float*)d_in[0];
  const int*   ei   = (const int*)d_in[1];
  const int*   batch= (const int*)d_in[2];
  const float* W1   = (const float*)d_in[3];
  const float* b1   = (const float*)d_in[4];
  const float* W2   = (const float*)d_in[5];
  const float* b2   = (const float*)d_in[6];
  const float* Wfc  = (const float*)d_in[7];
  const float* bfc  = (const float*)d_in[8];
  float* outp = (float*)d_out;

  const int N = in_sizes[0] / CH;       // 100000
  const int E = in_sizes[1] / 2;        // 3200000
  const int* src = ei;
  const int* dst = ei + E;
  const int NBUCK = (N + BW - 1) >> BSHIFT;   // 196

  // Workspace carve (256B aligned)
  char* w = (char*)d_ws;
  size_t o = 0;
  auto carve = [&](size_t bytes) -> void* {
    o = (o + 255) & ~(size_t)255;
    void* p = w + o;
    o += bytes;
    return p;
  };
  int*    offs   = (int*)   carve((size_t)(N + 1) * 4);
  int*    gbcnt  = (int*)   carve(MAXB * 4);
  int*    ebase  = (int*)   carve((MAXB + 1) * 4);
  int*    gcur   = (int*)   carve(MAXB * 4);
  int*    csr    = (int*)   carve((size_t)E * 4);
  float*  dinv   = (float*) carve((size_t)N * 4);
  __half* xsbuf  = (__half*)carve((size_t)N * CH * 2);  // fp16 gather buffer
  float*  hbuf   = (float*) carve((size_t)N * CH * 4);  // fp32 h between stages
  float*  gsum   = (float*) carve((size_t)NGRAPH * CH * 4);
  int*    gcnt   = (int*)   carve((size_t)NGRAPH * 4);
  (void)ws_size;

  // ebuf aliases hbuf (dead until agg layer-1 writes it): needs E*8 = 25.6MB
  int2* ebuf = (int2*)hbuf;

  hipMemsetAsync(gbcnt, 0, MAXB * 4, stream);
  hipMemsetAsync(gsum,  0, (size_t)NGRAPH * CH * 4, stream);
  hipMemsetAsync(gcnt,  0, (size_t)NGRAPH * 4, stream);

  // CSR build (bucketed counting sort)
  k_hist   <<<512, 256, 0, stream>>>(dst, gbcnt, E);
  k_bscan  <<<1, MAXB, 0, stream>>>(gbcnt, ebase, gcur);
  k_scatter<<<(E + 8191) / 8192, 1024, 0, stream>>>(src, dst, gcur, ebuf, E);
  k_build  <<<NBUCK, 1024, 0, stream>>>(ebuf, ebase, offs, dinv, csr, N, E, NBUCK);

  const int GB = (N + 127) / 128;
  const int AB = (N + 3) / 4;
  const int NB = (N + 255) / 256;

  // Layer 1: xs = fp16((x@W1)*dinv) ; h = relu(agg(xs)*dinv + b1)  (fp32)
  k_gemm_scale<<<GB, 256, 0, stream>>>(x, W1, dinv, xsbuf, N);
  k_agg<<<AB, 256, 0, stream>>>(xsbuf, csr, offs, dinv, b1, hbuf, N);
  // Layer 2
  k_gemm_scale<<<GB, 256, 0, stream>>>(hbuf, W2, dinv, xsbuf, N);
  k_agg<<<AB, 256, 0, stream>>>(xsbuf, csr, offs, dinv, b2, hbuf, N);

  // Pool + FC
  k_pool<<<GB, 128, 0, stream>>>(hbuf, batch, gsum, N);
  k_gcnt<<<NB, 256, 0, stream>>>(batch, gcnt, N);
  k_fc<<<NGRAPH, 64, 0, stream>>>(gsum, gcnt, Wfc, bfc, outp);
  (void)out_size; (void)n_in;
}

// Round 4
// 580.543 us; speedup vs baseline: 2.1395x; 1.2434x over previous
//
#include <hip/hip_runtime.h>
#include <hip/hip_bf16.h>
#include <hip/hip_fp16.h>

// Problem constants (match reference)
static constexpr int CH     = 128;   // IN_CH == HID
static constexpr int NCLS   = 32;
static constexpr int NGRAPH = 256;

// Bucketed CSR build: buckets are 512-node ranges (bucket = dst >> 9).
static constexpr int BSHIFT = 9;
static constexpr int BW     = 1 << BSHIFT;   // 512 nodes per bucket
static constexpr int MAXB   = 256;

// ---------------------------------------------------------------------------
// 1) bucket histogram (LDS-aggregated)
// ---------------------------------------------------------------------------
__global__ __launch_bounds__(256) void k_hist(const int* __restrict__ dst,
                                              int* __restrict__ gbcnt, int E) {
  __shared__ int h[MAXB];
  int t = threadIdx.x;
  h[t] = 0;
  __syncthreads();
  for (int i = blockIdx.x * 256 + t; i < E; i += gridDim.x * 256)
    atomicAdd(&h[dst[i] >> BSHIFT], 1);
  __syncthreads();
  if (h[t]) atomicAdd(&gbcnt[t], h[t]);
}

// ---------------------------------------------------------------------------
// 2) scan bucket counts -> ebase[257]; init bucket cursors
// ---------------------------------------------------------------------------
__global__ __launch_bounds__(256) void k_bscan(const int* __restrict__ gbcnt,
                                               int* __restrict__ ebase,
                                               int* __restrict__ gcur) {
  __shared__ int s[MAXB];
  int t = threadIdx.x;
  int v0 = gbcnt[t];
  s[t] = v0;
  __syncthreads();
  for (int st = 1; st < MAXB; st <<= 1) {
    int v = (t >= st) ? s[t - st] : 0;
    __syncthreads();
    s[t] += v;
    __syncthreads();
  }
  int ex = s[t] - v0;
  ebase[t] = ex;
  gcur[t]  = ex;
  if (t == MAXB - 1) ebase[MAXB] = s[t];
}

// ---------------------------------------------------------------------------
// 3) scatter (src,dst) pairs into bucket-ordered edge array
// ---------------------------------------------------------------------------
__global__ __launch_bounds__(1024) void k_scatter(
    const int* __restrict__ src, const int* __restrict__ dst,
    int* __restrict__ gcur, int2* __restrict__ ebuf, int E) {
  __shared__ int bcnt[MAXB];
  __shared__ int bbase[MAXB];
  int t = threadIdx.x;
  if (t < MAXB) bcnt[t] = 0;
  __syncthreads();
  int base = blockIdx.x * 8192;
  int s_[8], d_[8], r_[8];
  #pragma unroll
  for (int j = 0; j < 8; ++j) {
    int i = base + j * 1024 + t;
    if (i < E) {
      s_[j] = src[i];
      d_[j] = dst[i];
      r_[j] = atomicAdd(&bcnt[d_[j] >> BSHIFT], 1);
    }
  }
  __syncthreads();
  if (t < MAXB && bcnt[t]) bbase[t] = atomicAdd(&gcur[t], bcnt[t]);
  __syncthreads();
  #pragma unroll
  for (int j = 0; j < 8; ++j) {
    int i = base + j * 1024 + t;
    if (i < E) {
      int b = d_[j] >> BSHIFT;
      ebuf[bbase[b] + r_[j]] = make_int2(s_[j], d_[j]);
    }
  }
}

// ---------------------------------------------------------------------------
// 4) per-bucket CSR build
// ---------------------------------------------------------------------------
__global__ __launch_bounds__(1024) void k_build(
    const int2* __restrict__ ebuf, const int* __restrict__ ebase,
    int* __restrict__ offs, float* __restrict__ dinv,
    int* __restrict__ csr, int N, int E, int NBUCK) {
  __shared__ int sdeg[BW];
  __shared__ int sscan[BW];
  int b = blockIdx.x;
  int t = threadIdx.x;
  int lo = b << BSHIFT;
  int e0 = ebase[b], e1 = ebase[b + 1];

  if (t < BW) sdeg[t] = 0;
  __syncthreads();
  for (int e = e0 + t; e < e1; e += 1024)
    atomicAdd(&sdeg[ebuf[e].y - lo], 1);
  __syncthreads();
  if (t < BW) sscan[t] = sdeg[t];
  __syncthreads();
  for (int st = 1; st < BW; st <<= 1) {
    int v = (t < BW && t >= st) ? sscan[t - st] : 0;
    __syncthreads();
    if (t < BW) sscan[t] += v;
    __syncthreads();
  }
  if (t < BW) {
    int ex = e0 + sscan[t] - sdeg[t];
    int n = lo + t;
    if (n < N) {
      offs[n] = ex;
      dinv[n] = 1.0f / sqrtf((float)(sdeg[t] + 1));
    }
    sscan[t] = ex;
  }
  if (b == NBUCK - 1 && t == 0) offs[N] = E;
  __syncthreads();
  for (int e = e0 + t; e < e1; e += 1024) {
    int2 p = ebuf[e];
    int pos = atomicAdd(&sscan[p.y - lo], 1);
    csr[pos] = p.x;
  }
}

// ---------------------------------------------------------------------------
// GEMM: C[r][:] = half( (A[r][:] @ W) * dinv[r] )     A:[M,128] fp32, C fp16
// ---------------------------------------------------------------------------
__global__ __launch_bounds__(256) void k_gemm_scale(
    const float* __restrict__ A, const float* __restrict__ W,
    const float* __restrict__ dinv, __half* __restrict__ C, int M) {
  __shared__ float As[128][33];
  __shared__ float Bs[32][128];
  int tid = threadIdx.x;
  int tx = tid & 15, ty = tid >> 4;
  int row0 = blockIdx.x * 128;
  float acc[8][8];
  #pragma unroll
  for (int i = 0; i < 8; ++i)
    #pragma unroll
    for (int j = 0; j < 8; ++j) acc[i][j] = 0.0f;

  for (int k0 = 0; k0 < CH; k0 += 32) {
    #pragma unroll
    for (int l = 0; l < 4; ++l) {
      int i = tid + l * 256;
      int r = i >> 3, c4 = (i & 7) << 2;
      int rr = row0 + r; if (rr >= M) rr = M - 1;
      float4 v = *(const float4*)(A + (size_t)rr * CH + k0 + c4);
      As[r][c4 + 0] = v.x; As[r][c4 + 1] = v.y;
      As[r][c4 + 2] = v.z; As[r][c4 + 3] = v.w;
    }
    #pragma unroll
    for (int l = 0; l < 4; ++l) {
      int i = tid + l * 256;
      int r = i >> 5, c4 = (i & 31) << 2;
      *(float4*)&Bs[r][c4] = *(const float4*)(W + (size_t)(k0 + r) * CH + c4);
    }
    __syncthreads();
    #pragma unroll
    for (int kk = 0; kk < 32; ++kk) {
      float a[8];
      #pragma unroll
      for (int i = 0; i < 8; ++i) a[i] = As[ty * 8 + i][kk];
      float4 b0 = *(const float4*)&Bs[kk][tx * 8];
      float4 b1 = *(const float4*)&Bs[kk][tx * 8 + 4];
      float b[8] = {b0.x, b0.y, b0.z, b0.w, b1.x, b1.y, b1.z, b1.w};
      #pragma unroll
      for (int i = 0; i < 8; ++i)
        #pragma unroll
        for (int j = 0; j < 8; ++j) acc[i][j] = fmaf(a[i], b[j], acc[i][j]);
    }
    __syncthreads();
  }
  #pragma unroll
  for (int i = 0; i < 8; ++i) {
    int r = row0 + ty * 8 + i;
    if (r < M) {
      float d = dinv[r];
      __half2 p0 = __floats2half2_rn(acc[i][0] * d, acc[i][1] * d);
      __half2 p1 = __floats2half2_rn(acc[i][2] * d, acc[i][3] * d);
      __half2 p2 = __floats2half2_rn(acc[i][4] * d, acc[i][5] * d);
      __half2 p3 = __floats2half2_rn(acc[i][6] * d, acc[i][7] * d);
      float4 ov;
      ((__half2*)&ov)[0] = p0; ((__half2*)&ov)[1] = p1;
      ((__half2*)&ov)[2] = p2; ((__half2*)&ov)[3] = p3;
      *((float4*)(C + (size_t)r * CH) + tx) = ov;   // 16B = 8 halfs
    }
  }
}

// ---------------------------------------------------------------------------
// Aggregation (pull, CSR)
// ---------------------------------------------------------------------------
__global__ __launch_bounds__(256) void k_agg(
    const __half* __restrict__ xs, const int* __restrict__ csr,
    const int* __restrict__ offs, const float* __restrict__ dinv,
    const float* __restrict__ bias, float* __restrict__ out, int N) {
  int node = blockIdx.x * 4 + (threadIdx.x >> 6);
  int lane = threadIdx.x & 63;
  if (node >= N) return;
  int beg = offs[node], end = offs[node + 1];
  const __half2* base = (const __half2*)xs;
  float2 self = __half22float2(base[(size_t)node * 64 + lane]);
  float ax = self.x, ay = self.y;
  float bx2 = 0.f, by2 = 0.f;
  int e = beg;
  for (; e + 3 < end; e += 4) {
    int s0 = csr[e], s1 = csr[e + 1], s2 = csr[e + 2], s3 = csr[e + 3];
    float2 v0 = __half22float2(base[(size_t)s0 * 64 + lane]);
    float2 v1 = __half22float2(base[(size_t)s1 * 64 + lane]);
    float2 v2 = __half22float2(base[(size_t)s2 * 64 + lane]);
    float2 v3 = __half22float2(base[(size_t)s3 * 64 + lane]);
    ax += v0.x + v2.x; ay += v0.y + v2.y;
    bx2 += v1.x + v3.x; by2 += v1.y + v3.y;
  }
  for (; e < end; ++e) {
    int s = csr[e];
    float2 v = __half22float2(base[(size_t)s * 64 + lane]);
    ax += v.x; ay += v.y;
  }
  ax += bx2; ay += by2;
  float d = dinv[node];
  float rx = fmaf(ax, d, bias[2 * lane]);
  float ry = fmaf(ay, d, bias[2 * lane + 1]);
  float2 r = {fmaxf(rx, 0.f), fmaxf(ry, 0.f)};
  ((float2*)out)[(size_t)node * 64 + lane] = r;
}

// ---------------------------------------------------------------------------
// Pool: batch sorted -> run-length accumulate, few atomics
// ---------------------------------------------------------------------------
__global__ __launch_bounds__(128) void k_pool(
    const float* __restrict__ h, const int* __restrict__ batch,
    float* __restrict__ gsum, int N) {
  int ch = threadIdx.x;
  int n0 = blockIdx.x * 128;
  int n1 = n0 + 128; if (n1 > N) n1 = N;
  if (n0 >= N) return;
  float acc = 0.f;
  int curg = batch[n0];
  for (int n = n0; n < n1; ++n) {
    int g = batch[n];
    if (g != curg) {
      atomicAdd(&gsum[curg * CH + ch], acc);
      acc = 0.f; curg = g;
    }
    acc += h[(size_t)n * CH + ch];
  }
  atomicAdd(&gsum[curg * CH + ch], acc);
}

// ---------------------------------------------------------------------------
// Graph run boundaries (batch is sorted; no atomics).
// gcnt[g] = gend[g] - gstart[g]; both zeroed so empty graphs give 0.
// ---------------------------------------------------------------------------
__global__ __launch_bounds__(256) void k_gbound(
    const int* __restrict__ batch, int* __restrict__ gstart,
    int* __restrict__ gend, int N) {
  int i = blockIdx.x * 256 + threadIdx.x;
  if (i >= N) return;
  int g = batch[i];
  if (i == 0 || batch[i - 1] != g) gstart[g] = i;
  if (i == N - 1 || batch[i + 1] != g) gend[g] = i + 1;
}

// ---------------------------------------------------------------------------
// FC
// ---------------------------------------------------------------------------
__global__ __launch_bounds__(64) void k_fc(
    const float* __restrict__ gsum, const int* __restrict__ gstart,
    const int* __restrict__ gend, const float* __restrict__ Wfc,
    const float* __restrict__ bfc, float* __restrict__ outp) {
  int g = blockIdx.x;
  int j = threadIdx.x;
  if (j >= NCLS) return;
  int cnt = gend[g] - gstart[g];
  float invc = 1.0f / fmaxf((float)cnt, 1.0f);
  float acc = 0.0f;
  for (int c = 0; c < CH; ++c)
    acc = fmaf(gsum[g * CH + c], Wfc[c * NCLS + j], acc);
  outp[g * NCLS + j] = fmaf(acc, invc, bfc[j]);
}

// ---------------------------------------------------------------------------
extern "C" void kernel_launch(void* const* d_in, const int* in_sizes, int n_in,
                              void* d_out, int out_size, void* d_ws, size_t ws_size,
                              hipStream_t stream) {
  const float* x    = (const float*)d_in[0];
  const int*   ei   = (const int*)d_in[1];
  const int*   batch= (const int*)d_in[2];
  const float* W1   = (const float*)d_in[3];
  const float* b1   = (const float*)d_in[4];
  const float* W2   = (const float*)d_in[5];
  const float* b2   = (const float*)d_in[6];
  const float* Wfc  = (const float*)d_in[7];
  const float* bfc  = (const float*)d_in[8];
  float* outp = (float*)d_out;

  const int N = in_sizes[0] / CH;       // 100000
  const int E = in_sizes[1] / 2;        // 3200000
  const int* src = ei;
  const int* dst = ei + E;
  const int NBUCK = (N + BW - 1) >> BSHIFT;   // 196

  // Workspace carve (256B aligned)
  char* w = (char*)d_ws;
  size_t o = 0;
  auto carve = [&](size_t bytes) -> void* {
    o = (o + 255) & ~(size_t)255;
    void* p = w + o;
    o += bytes;
    return p;
  };
  int*    offs   = (int*)   carve((size_t)(N + 1) * 4);
  int*    gbcnt  = (int*)   carve(MAXB * 4);
  int*    ebase  = (int*)   carve((MAXB + 1) * 4);
  int*    gcur   = (int*)   carve(MAXB * 4);
  int*    csr    = (int*)   carve((size_t)E * 4);
  float*  dinv   = (float*) carve((size_t)N * 4);
  __half* xsbuf  = (__half*)carve((size_t)N * CH * 2);  // fp16 gather buffer
  float*  hbuf   = (float*) carve((size_t)N * CH * 4);  // fp32 h between stages
  float*  gsum   = (float*) carve((size_t)NGRAPH * CH * 4);
  int*    gstart = (int*)   carve((size_t)NGRAPH * 4);
  int*    gend   = (int*)   carve((size_t)NGRAPH * 4);
  (void)ws_size;

  // ebuf aliases hbuf (dead until agg layer-1 writes it): needs E*8 = 25.6MB
  int2* ebuf = (int2*)hbuf;

  hipMemsetAsync(gbcnt,  0, MAXB * 4, stream);
  hipMemsetAsync(gsum,   0, (size_t)NGRAPH * CH * 4, stream);
  hipMemsetAsync(gstart, 0, (size_t)NGRAPH * 4, stream);
  hipMemsetAsync(gend,   0, (size_t)NGRAPH * 4, stream);

  // CSR build (bucketed counting sort)
  k_hist   <<<512, 256, 0, stream>>>(dst, gbcnt, E);
  k_bscan  <<<1, MAXB, 0, stream>>>(gbcnt, ebase, gcur);
  k_scatter<<<(E + 8191) / 8192, 1024, 0, stream>>>(src, dst, gcur, ebuf, E);
  k_build  <<<NBUCK, 1024, 0, stream>>>(ebuf, ebase, offs, dinv, csr, N, E, NBUCK);

  const int GB = (N + 127) / 128;
  const int AB = (N + 3) / 4;
  const int NB = (N + 255) / 256;

  // Layer 1: xs = fp16((x@W1)*dinv) ; h = relu(agg(xs)*dinv + b1)  (fp32)
  k_gemm_scale<<<GB, 256, 0, stream>>>(x, W1, dinv, xsbuf, N);
  k_agg<<<AB, 256, 0, stream>>>(xsbuf, csr, offs, dinv, b1, hbuf, N);
  // Layer 2
  k_gemm_scale<<<GB, 256, 0, stream>>>(hbuf, W2, dinv, xsbuf, N);
  k_agg<<<AB, 256, 0, stream>>>(xsbuf, csr, offs, dinv, b2, hbuf, N);

  // Pool + FC
  k_pool<<<GB, 128, 0, stream>>>(hbuf, batch, gsum, N);
  k_gbound<<<NB, 256, 0, stream>>>(batch, gstart, gend, N);
  k_fc<<<NGRAPH, 64, 0, stream>>>(gsum, gstart, gend, Wfc, bfc, outp);
  (void)out_size; (void)n_in;
}